// Round 2
// 511.448 us; speedup vs baseline: 1.1199x; 1.1199x over previous
//
#include <hip/hip_runtime.h>
#include <math.h>

#define BB 16
#define TT 1024
#define SS 2048
#define CC 256
#define EE 256
#define NSUB 103        // (SS-1)/STRIDE + 1
#define MAXS 20
#define STRIDE_ 20

static constexpr float RSQRT2  = 0.70710678118654752440f;   // sqrt(0.5)
static constexpr float SQRT_S  = 45.25483399593904f;        // s*sqrt(1/s) = sqrt(2048)
static constexpr float GNORM   = 0.13298076013381093f;      // 1/(sqrt(2*pi)*3)
static constexpr float INV2S2  = 0.055555555555555555f;     // 1/(2*sigma^2)

typedef __attribute__((ext_vector_type(8))) __bf16 bf16x8;
typedef __attribute__((ext_vector_type(4))) float  f32x4;

__device__ __forceinline__ float wave_sum(float v) {
    #pragma unroll
    for (int o = 32; o; o >>= 1) v += __shfl_down(v, o);
    return v;
}
__device__ __forceinline__ float wave_max(float v) {
    #pragma unroll
    for (int o = 32; o; o >>= 1) v = fmaxf(v, __shfl_down(v, o));
    return v;
}
__device__ __forceinline__ unsigned short f2bf(float f) {   // RNE
    unsigned int u = __float_as_uint(f);
    u = (u + 0x7FFFu + ((u >> 16) & 1u)) >> 16;
    return (unsigned short)u;
}
__device__ __forceinline__ float bf2f(unsigned short s) {
    return __uint_as_float(((unsigned int)s) << 16);
}

#define GLD_LDS16(g, l) __builtin_amdgcn_global_load_lds(                      \
    (const __attribute__((address_space(1))) void*)(g),                        \
    (__attribute__((address_space(3))) void*)(l), 16, 0, 0)

// fp32 -> bf16 cast, 4 elems/thread
__global__ __launch_bounds__(256) void k_cast_bf16(const float* __restrict__ in,
                                                   unsigned short* __restrict__ out, int n4)
{
    const int i = blockIdx.x * 256 + threadIdx.x;
    if (i < n4) {
        const float4 v = reinterpret_cast<const float4*>(in)[i];
        union { unsigned short u[4]; unsigned long long v8; } pk;
        pk.u[0] = f2bf(v.x); pk.u[1] = f2bf(v.y);
        pk.u[2] = f2bf(v.z); pk.u[3] = f2bf(v.w);
        reinterpret_cast<unsigned long long*>(out)[i] = pk.v8;
    }
}

// fp32 [Bz][R][Cc] -> bf16 [Bz][Cc][R] transpose. grid (R/64, Cc/64, Bz), 256 thr
__global__ __launch_bounds__(256) void k_transpose_bf16(
    const float* __restrict__ in, unsigned short* __restrict__ out, int R, int Cc)
{
    __shared__ float t[64][65];
    const int b = blockIdx.z;
    const int r0 = blockIdx.x * 64, c0 = blockIdx.y * 64;
    const float* ip = in + (size_t)b * R * Cc;
    unsigned short* op = out + (size_t)b * R * Cc;
    const int tx = threadIdx.x & 63, ty = threadIdx.x >> 6;  // ty in [0,4)
    #pragma unroll
    for (int i = 0; i < 16; ++i)
        t[ty + 4 * i][tx] = ip[(size_t)(r0 + ty + 4 * i) * Cc + c0 + tx];
    __syncthreads();
    #pragma unroll
    for (int i = 0; i < 16; ++i)
        op[(size_t)(c0 + ty + 4 * i) * R + r0 + tx] = f2bf(t[tx][ty + 4 * i]);
}

// ---------------------------------------------------------------------------
// bf16 MFMA GEMM, 128x128 tile (m97 pattern): A [Bz][M][K] bf16, Bt [Bz][N][K]
// bf16 (B^T), O[m,n] = epilogue(sum_k A[m,k]*Bt[n,k]).
// MODE 0: Of = acc*scale
// MODE 1: Of = (acc + bias[n] + add[m,n])*RSQRT2
// MODE 2: Ob = bf16((acc + bias[n] + add[m,n])*RSQRT2)
// MODE 3: Ob = bf16(acc*scale)
// Use when grid is large (>=2 blocks/CU).
// ---------------------------------------------------------------------------
template<int MODE>
__global__ __launch_bounds__(256) void k_gemm_mfma(
    const unsigned short* __restrict__ Abase,
    const unsigned short* __restrict__ Btbase,
    const float* __restrict__ bias, const float* __restrict__ add,
    float* __restrict__ Obase, unsigned short* __restrict__ Obbase,
    int M, int Nn, int K, float scale)
{
    __shared__ unsigned short As[128 * 32];
    __shared__ unsigned short Bs[128 * 32];
    const int b  = blockIdx.z;
    const int m0 = blockIdx.x * 128;
    const int n0 = blockIdx.y * 128;
    const unsigned short* A  = Abase  + (size_t)b * M  * K;
    const unsigned short* Bt = Btbase + (size_t)b * Nn * K;

    const int tid  = threadIdx.x;
    const int w    = tid >> 6;          // wave 0..3
    const int lane = tid & 63;
    const int wm   = w & 1, wn = w >> 1;
    const int sr   = lane >> 2;         // staging row within 16-row chunk
    const int sk   = (lane & 3) * 8;    // staging k offset (elements)

    const unsigned short* ga0 = A  + (size_t)(m0 + w * 32 + sr) * K + sk;
    const unsigned short* ga1 = ga0 + (size_t)16 * K;
    const unsigned short* gb0 = Bt + (size_t)(n0 + w * 32 + sr) * K + sk;
    const unsigned short* gb1 = gb0 + (size_t)16 * K;
    unsigned short* la0 = As + w * 1024;
    unsigned short* la1 = As + w * 1024 + 512;
    unsigned short* lb0 = Bs + w * 1024;
    unsigned short* lb1 = Bs + w * 1024 + 512;

    const int fr = lane & 15;           // m/n within a 16-tile
    const int q  = (lane >> 4) * 8;     // k offset of this lane's quad

    f32x4 acc[4][4];
    #pragma unroll
    for (int i = 0; i < 4; ++i)
        #pragma unroll
        for (int j = 0; j < 4; ++j)
            acc[i][j] = (f32x4){0.f, 0.f, 0.f, 0.f};

    for (int k0 = 0; k0 < K; k0 += 32) {
        GLD_LDS16(ga0, la0);
        GLD_LDS16(ga1, la1);
        GLD_LDS16(gb0, lb0);
        GLD_LDS16(gb1, lb1);
        ga0 += 32; ga1 += 32; gb0 += 32; gb1 += 32;
        __syncthreads();
        bf16x8 af[4], bfr[4];
        #pragma unroll
        for (int i = 0; i < 4; ++i) {
            af[i]  = *reinterpret_cast<const bf16x8*>(&As[(wm * 64 + i * 16 + fr) * 32 + q]);
            bfr[i] = *reinterpret_cast<const bf16x8*>(&Bs[(wn * 64 + i * 16 + fr) * 32 + q]);
        }
        #pragma unroll
        for (int i = 0; i < 4; ++i)
            #pragma unroll
            for (int j = 0; j < 4; ++j)
                acc[i][j] = __builtin_amdgcn_mfma_f32_16x16x32_bf16(af[i], bfr[j], acc[i][j], 0, 0, 0);
        __syncthreads();
    }

    // C/D layout: col = lane&15, row = (lane>>4)*4 + reg   [m89-verified]
    float* Of = (MODE == 0 || MODE == 1) ? Obase + (size_t)b * M * Nn : nullptr;
    unsigned short* Ob = (MODE == 2 || MODE == 3) ? Obbase + (size_t)b * M * Nn : nullptr;
    const int rb = (lane >> 4) * 4;
    #pragma unroll
    for (int i = 0; i < 4; ++i)
        #pragma unroll
        for (int j = 0; j < 4; ++j) {
            const int n = n0 + wn * 64 + j * 16 + fr;
            #pragma unroll
            for (int r2 = 0; r2 < 4; ++r2) {
                const int m = m0 + wm * 64 + i * 16 + rb + r2;
                const size_t idx = (size_t)m * Nn + n;
                if (MODE == 0) {
                    Of[idx] = acc[i][j][r2] * scale;
                } else if (MODE == 1) {
                    Of[idx] = (acc[i][j][r2] + bias[n] + add[idx]) * RSQRT2;
                } else if (MODE == 2) {
                    Ob[idx] = f2bf((acc[i][j][r2] + bias[n] + add[idx]) * RSQRT2);
                } else {
                    Ob[idx] = f2bf(acc[i][j][r2] * scale);
                }
            }
        }
}

// ---------------------------------------------------------------------------
// Same GEMM, 64x128 tile, 12 KB LDS. Doubles block count for the N=256 GEMMs
// whose 128x128 grid is exactly 256 blocks (1 block/CU = 1 wave/SIMD, zero
// TLP to hide the global_load_lds drain). 3 GLD + 8 MFMA per wave per K-step.
// ---------------------------------------------------------------------------
template<int MODE>
__global__ __launch_bounds__(256) void k_gemm64(
    const unsigned short* __restrict__ Abase,
    const unsigned short* __restrict__ Btbase,
    const float* __restrict__ bias, const float* __restrict__ add,
    float* __restrict__ Obase, unsigned short* __restrict__ Obbase,
    int M, int Nn, int K, float scale)
{
    __shared__ unsigned short As[64 * 32];
    __shared__ unsigned short Bs[128 * 32];
    const int b  = blockIdx.z;
    const int m0 = blockIdx.x * 64;
    const int n0 = blockIdx.y * 128;
    const unsigned short* A  = Abase  + (size_t)b * M  * K;
    const unsigned short* Bt = Btbase + (size_t)b * Nn * K;

    const int tid  = threadIdx.x;
    const int w    = tid >> 6;          // wave 0..3
    const int lane = tid & 63;
    const int wm   = w & 1, wn = w >> 1;
    const int sr   = lane >> 2;
    const int sk   = (lane & 3) * 8;

    // A: wave w stages rows [w*16, w*16+16)  -> As + w*512 (lane-linear)
    const unsigned short* ga0 = A  + (size_t)(m0 + w * 16 + sr) * K + sk;
    // B: wave w stages rows [w*32, w*32+32)
    const unsigned short* gb0 = Bt + (size_t)(n0 + w * 32 + sr) * K + sk;
    const unsigned short* gb1 = gb0 + (size_t)16 * K;
    unsigned short* la0 = As + w * 512;
    unsigned short* lb0 = Bs + w * 1024;
    unsigned short* lb1 = Bs + w * 1024 + 512;

    const int fr = lane & 15;
    const int q  = (lane >> 4) * 8;

    f32x4 acc[2][4];
    #pragma unroll
    for (int i = 0; i < 2; ++i)
        #pragma unroll
        for (int j = 0; j < 4; ++j)
            acc[i][j] = (f32x4){0.f, 0.f, 0.f, 0.f};

    for (int k0 = 0; k0 < K; k0 += 32) {
        GLD_LDS16(ga0, la0);
        GLD_LDS16(gb0, lb0);
        GLD_LDS16(gb1, lb1);
        ga0 += 32; gb0 += 32; gb1 += 32;
        __syncthreads();
        bf16x8 af[2], bfr[4];
        #pragma unroll
        for (int i = 0; i < 2; ++i)
            af[i]  = *reinterpret_cast<const bf16x8*>(&As[(wm * 32 + i * 16 + fr) * 32 + q]);
        #pragma unroll
        for (int j = 0; j < 4; ++j)
            bfr[j] = *reinterpret_cast<const bf16x8*>(&Bs[(wn * 64 + j * 16 + fr) * 32 + q]);
        #pragma unroll
        for (int i = 0; i < 2; ++i)
            #pragma unroll
            for (int j = 0; j < 4; ++j)
                acc[i][j] = __builtin_amdgcn_mfma_f32_16x16x32_bf16(af[i], bfr[j], acc[i][j], 0, 0, 0);
        __syncthreads();
    }

    float* Of = (MODE == 0 || MODE == 1) ? Obase + (size_t)b * M * Nn : nullptr;
    unsigned short* Ob = (MODE == 2 || MODE == 3) ? Obbase + (size_t)b * M * Nn : nullptr;
    const int rb = (lane >> 4) * 4;
    #pragma unroll
    for (int i = 0; i < 2; ++i)
        #pragma unroll
        for (int j = 0; j < 4; ++j) {
            const int n = n0 + wn * 64 + j * 16 + fr;
            #pragma unroll
            for (int r2 = 0; r2 < 4; ++r2) {
                const int m = m0 + wm * 32 + i * 16 + rb + r2;
                const size_t idx = (size_t)m * Nn + n;
                if (MODE == 0) {
                    Of[idx] = acc[i][j][r2] * scale;
                } else if (MODE == 1) {
                    Of[idx] = (acc[i][j][r2] + bias[n] + add[idx]) * RSQRT2;
                } else if (MODE == 2) {
                    Ob[idx] = f2bf((acc[i][j][r2] + bias[n] + add[idx]) * RSQRT2);
                } else {
                    Ob[idx] = f2bf(acc[i][j][r2] * scale);
                }
            }
        }
}

// Row softmax over S=2048. Input: bf16 scores in attnb. Output: fp32 attn
// (required output) + normalized bf16 back into attnb IN PLACE (each block
// owns its full row; each thread rewrites only the 8 elems it read).
__global__ __launch_bounds__(256) void k_softmax(float* __restrict__ attn,
                                                 unsigned short* __restrict__ attnb)
{
    float* p = attn + (size_t)blockIdx.x * SS;
    unsigned short* pb = attnb + (size_t)blockIdx.x * SS;
    const int tid = threadIdx.x;
    __shared__ float w[4];
    union { unsigned short u[8]; uint4 v4; } in;
    in.v4 = *reinterpret_cast<const uint4*>(&pb[tid * 8]);
    float v[8];
    #pragma unroll
    for (int i = 0; i < 8; ++i) v[i] = bf2f(in.u[i]);
    float mx = -INFINITY;
    #pragma unroll
    for (int i = 0; i < 8; ++i) mx = fmaxf(mx, v[i]);
    float wm = wave_max(mx);
    if ((tid & 63) == 0) w[tid >> 6] = wm;
    __syncthreads();
    const float m = fmaxf(fmaxf(w[0], w[1]), fmaxf(w[2], w[3]));
    float s = 0.f;
    #pragma unroll
    for (int i = 0; i < 8; ++i) { v[i] = expf(v[i] - m); s += v[i]; }
    __syncthreads();
    float wsv = wave_sum(s);
    if ((tid & 63) == 0) w[tid >> 6] = wsv;
    __syncthreads();
    const float inv = 1.0f / (w[0] + w[1] + w[2] + w[3]);
    float4 o0, o1;
    o0.x = v[0] * inv; o0.y = v[1] * inv; o0.z = v[2] * inv; o0.w = v[3] * inv;
    o1.x = v[4] * inv; o1.y = v[5] * inv; o1.z = v[6] * inv; o1.w = v[7] * inv;
    *reinterpret_cast<float4*>(&p[tid * 8])     = o0;
    *reinterpret_cast<float4*>(&p[tid * 8 + 4]) = o1;
    union { unsigned short u[8]; uint4 v4; } pk;
    pk.u[0] = f2bf(o0.x); pk.u[1] = f2bf(o0.y); pk.u[2] = f2bf(o0.z); pk.u[3] = f2bf(o0.w);
    pk.u[4] = f2bf(o1.x); pk.u[5] = f2bf(o1.y); pk.u[6] = f2bf(o1.z); pk.u[7] = f2bf(o1.w);
    *reinterpret_cast<uint4*>(&pb[tid * 8]) = pk.v4;
}

// x_mean[b,s] = mean_t attn[b,t,s], from bf16 copy. grid (S/256, B)
__global__ __launch_bounds__(256) void k_xmean(const unsigned short* __restrict__ attnb,
                                               float* __restrict__ xmean)
{
    const int b = blockIdx.y;
    const int s = blockIdx.x * 256 + threadIdx.x;
    const unsigned short* p = attnb + (size_t)b * TT * SS + s;
    float acc = 0.f;
    #pragma unroll 8
    for (int t = 0; t < TT; ++t) acc += bf2f(p[(size_t)t * SS]);
    xmean[(size_t)b * SS + s] = acc * (1.0f / TT);
}

// ns[b,n,:] = enc_values[b, n*STRIDE, :]/||.||;  aa[b,n] = xmean[b, n*STRIDE]
// Also zeroes klp (stream-ordered before k_dist_kl's atomicAdds).
__global__ __launch_bounds__(256) void k_ns(const float* __restrict__ ev,
                                            const float* __restrict__ xmean,
                                            float* __restrict__ ns, float* __restrict__ aa,
                                            float* __restrict__ klp)
{
    const int n = blockIdx.x, b = blockIdx.y;
    const int tid = threadIdx.x;
    if (n == 0 && b == 0 && tid == 0) klp[0] = 0.0f;
    const float* rowp = ev + ((size_t)b * SS + (size_t)n * STRIDE_) * EE;
    const float v = rowp[tid];
    __shared__ float w[4];
    float r = wave_sum(v * v);
    if ((tid & 63) == 0) w[tid >> 6] = r;
    __syncthreads();
    const float nrm = sqrtf(w[0] + w[1] + w[2] + w[3]);
    ns[((size_t)b * NSUB + n) * EE + tid] = v / nrm;
    if (tid == 0) aa[b * NSUB + n] = xmean[(size_t)b * SS + n * STRIDE_];
}

// L[b,i,j] = (aa_i*aa_j) * dot(ns_i, ns_j).  grid (N, B), 128 thr
__global__ __launch_bounds__(128) void k_L(const float* __restrict__ ns,
                                           const float* __restrict__ aa,
                                           float* __restrict__ Lm)
{
    const int i = blockIdx.x, b = blockIdx.y;
    const int tid = threadIdx.x;
    __shared__ float nsi[EE];
    nsi[tid]       = ns[((size_t)b * NSUB + i) * EE + tid];
    nsi[tid + 128] = ns[((size_t)b * NSUB + i) * EE + tid + 128];
    __syncthreads();
    const float ai = aa[b * NSUB + i];
    for (int j = tid; j < NSUB; j += 128) {
        const float* rj = ns + ((size_t)b * NSUB + j) * EE;
        float d = 0.f;
        #pragma unroll 4
        for (int e = 0; e < EE; ++e) d += nsi[e] * rj[e];
        Lm[((size_t)b * NSUB + i) * NSUB + j] = d * ai * aa[b * NSUB + j];
    }
}

// Greedy MAP DPP (Cholesky) — one block (128 thr = 2 waves) per batch.
__global__ __launch_bounds__(128) void k_bfgm(const float* __restrict__ Lm,
                                              float* __restrict__ mu)
{
    const int b = blockIdx.x;
    const int tid = threadIdx.x;
    const float* L = Lm + (size_t)b * NSUB * NSUB;
    __shared__ float D[128], mask[128], Cm[128][MAXS], cj[MAXS];
    __shared__ float rv[2];
    __shared__ int   ri[2];
    __shared__ int   Jsh;
    const bool act = tid < NSUB;
    D[tid]    = act ? L[(size_t)tid * NSUB + tid] : 0.0f;
    mask[tid] = act ? 1.0f : 0.0f;
    #pragma unroll
    for (int k = 0; k < MAXS; ++k) Cm[tid][k] = 0.0f;
    __syncthreads();

    auto argmax_step = [&](int t) {
        float key = act ? logf(D[tid] * mask[tid]) : -INFINITY;
        if (isnan(key)) key = INFINITY;   // numpy argmax: NaN wins
        float v = key; int idx = tid;
        #pragma unroll
        for (int o = 32; o; o >>= 1) {
            float ov = __shfl_down(v, o); int oi = __shfl_down(idx, o);
            if (ov > v || (ov == v && oi < idx)) { v = ov; idx = oi; }
        }
        if ((tid & 63) == 0) { rv[tid >> 6] = v; ri[tid >> 6] = idx; }
        __syncthreads();
        if (tid == 0) {
            const int J = (rv[1] > rv[0] || (rv[1] == rv[0] && ri[1] < ri[0])) ? ri[1] : ri[0];
            Jsh = J; mask[J] = 0.0f; mu[b * MAXS + t] = (float)J;
        }
        __syncthreads();
    };

    argmax_step(0);
    for (int t = 1; t < MAXS; ++t) {
        if (tid < MAXS) cj[tid] = Cm[Jsh][tid];
        __syncthreads();
        const int J = Jsh;
        const float dj = D[J];
        float e = 0.0f;
        if (act) {
            const float Ljn = L[(size_t)J * NSUB + tid];
            float cd = 0.f;
            #pragma unroll
            for (int k = 0; k < MAXS; ++k) cd += Cm[tid][k] * cj[k];
            e = (Ljn - cd) / dj * mask[tid];
        }
        Cm[tid][t] = e;
        D[tid] -= e * e;
        __syncthreads();
        argmax_step(t);
    }
}

// dist[b,:] = softmax_s( sum_m gauss(s - mu[b,m]) ) computed in registers,
// immediately consumed into the KL partial:  klp -= sum_s xm*(log xm - dist).
// grid B, 256 thr. klp pre-zeroed by k_ns.
__global__ __launch_bounds__(256) void k_dist_kl(const float* __restrict__ mu,
                                                 const float* __restrict__ xmean,
                                                 float* __restrict__ outkl)
{
    const int b = blockIdx.x;
    const int tid = threadIdx.x;
    __shared__ float mus[MAXS];
    __shared__ float w[4];
    if (tid < MAXS) mus[tid] = mu[b * MAXS + tid];
    __syncthreads();
    float g[8];
    float mx = -INFINITY;
    #pragma unroll
    for (int i = 0; i < 8; ++i) {
        const float s = (float)(tid + (i << 8));
        float acc = 0.f;
        #pragma unroll
        for (int m = 0; m < MAXS; ++m) { const float z = s - mus[m]; acc += expf(-(z * z) * INV2S2); }
        g[i] = acc * GNORM;
        mx = fmaxf(mx, g[i]);
    }
    float wm = wave_max(mx);
    if ((tid & 63) == 0) w[tid >> 6] = wm;
    __syncthreads();
    const float m = fmaxf(fmaxf(w[0], w[1]), fmaxf(w[2], w[3]));
    float sum = 0.f;
    #pragma unroll
    for (int i = 0; i < 8; ++i) { g[i] = expf(g[i] - m); sum += g[i]; }
    __syncthreads();
    float wsv = wave_sum(sum);
    if ((tid & 63) == 0) w[tid >> 6] = wsv;
    __syncthreads();
    const float inv = 1.0f / (w[0] + w[1] + w[2] + w[3]);
    // KL partial over this batch's 2048 entries
    float part = 0.f;
    #pragma unroll
    for (int i = 0; i < 8; ++i) {
        const float xm = xmean[(size_t)b * SS + tid + (i << 8)];
        part += xm * (logf(xm) - g[i] * inv);
    }
    __syncthreads();
    float wp = wave_sum(part);
    if ((tid & 63) == 0) w[tid >> 6] = wp;
    __syncthreads();
    if (tid == 0) atomicAdd(outkl, -(w[0] + w[1] + w[2] + w[3]));
}

extern "C" void kernel_launch(void* const* d_in, const int* in_sizes, int n_in,
                              void* d_out, int out_size, void* d_ws, size_t ws_size,
                              hipStream_t stream)
{
    const float* x     = (const float*)d_in[0];   // (B,T,C)
    const float* te    = (const float*)d_in[1];   // (B,T,E)
    const float* keys  = (const float*)d_in[2];   // (B,E,S)
    const float* vals  = (const float*)d_in[3];   // (B,S,E)
    const float* W_in  = (const float*)d_in[4];   // (E,C)
    const float* b_in  = (const float*)d_in[5];   // (E)
    const float* W_out = (const float*)d_in[6];   // (C,E)
    const float* b_out = (const float*)d_in[7];   // (C)

    float* outp = (float*)d_out;                       // (B,T,C)
    float* attn = outp + (size_t)BB * TT * CC;         // (B,T,S) fp32
    float* klp  = attn + (size_t)BB * TT * SS;         // scalar

    // workspace (~130 MB)
    unsigned short* X       = (unsigned short*)d_ws;
    unsigned short* x_bf    = X;                                       // B*T*C
    unsigned short* Win_bf  = x_bf   + (size_t)BB * TT * CC;           // E*C
    unsigned short* Wout_bf = Win_bf + (size_t)EE * CC;                // C*E
    unsigned short* h_bf    = Wout_bf+ (size_t)CC * EE;                // B*T*E
    unsigned short* keysT   = h_bf   + (size_t)BB * TT * EE;           // B*S*E
    unsigned short* valsT   = keysT  + (size_t)BB * SS * EE;           // B*E*S
    unsigned short* attnb   = valsT  + (size_t)BB * EE * SS;           // B*T*S (scores, then attn)
    unsigned short* mid_bf  = attnb  + (size_t)BB * TT * SS;           // B*T*E
    float* fws   = (float*)(mid_bf + (size_t)BB * TT * EE + 8);
    float* xmean = fws;                                  // (B,S)
    float* ns    = xmean + (size_t)BB * SS;              // (B,N,E)
    float* aa    = ns    + (size_t)BB * NSUB * EE;       // (B,N)
    float* Lm    = aa    + (size_t)BB * NSUB;            // (B,N,N)
    float* mu    = Lm    + (size_t)BB * NSUB * NSUB;     // (B,MAXS)

    // casts
    k_cast_bf16<<<(BB * TT * CC / 4 + 255) / 256, 256, 0, stream>>>(x, x_bf, BB * TT * CC / 4);
    k_cast_bf16<<<(EE * CC / 4 + 255) / 256, 256, 0, stream>>>(W_in, Win_bf, EE * CC / 4);
    k_cast_bf16<<<(CC * EE / 4 + 255) / 256, 256, 0, stream>>>(W_out, Wout_bf, CC * EE / 4);
    // 1) h_bf = bf16((x @ W_in^T + b_in + te) * sqrt(.5))   [64-tile, 512 blocks]
    k_gemm64<2><<<dim3(256, 2, 1), 256, 0, stream>>>(
        x_bf, Win_bf, b_in, te, nullptr, h_bf, BB * TT, CC, CC, 1.0f);
    // 2) keysT[b,s,e] = keys[b,e,s] (bf16)
    k_transpose_bf16<<<dim3(4, 32, BB), 256, 0, stream>>>(keys, keysT, EE, SS);
    // 3) scores (bf16) -> attnb   [128-tile, 2048 blocks]
    k_gemm_mfma<3><<<dim3(8, 16, BB), 256, 0, stream>>>(
        h_bf, keysT, nullptr, nullptr, nullptr, attnb, TT, SS, EE, 1.0f);
    // 4) valsT[b,e,s] = vals[b,s,e] (bf16)
    k_transpose_bf16<<<dim3(32, 4, BB), 256, 0, stream>>>(vals, valsT, SS, EE);
    // 5) softmax: attnb(scores bf16) -> attn fp32 (output) + attnb bf16 in place
    k_softmax<<<BB * TT, 256, 0, stream>>>(attn, attnb);
    // 6) x_mean from bf16 attn
    k_xmean<<<dim3(SS / 256, BB), 256, 0, stream>>>(attnb, xmean);
    // 7) DPP chain (k_ns also zeroes klp for the k_dist_kl atomics)
    k_ns<<<dim3(NSUB, BB), 256, 0, stream>>>(vals, xmean, ns, aa, klp);
    k_L<<<dim3(NSUB, BB), 128, 0, stream>>>(ns, aa, Lm);
    k_bfgm<<<BB, 128, 0, stream>>>(Lm, mu);
    k_dist_kl<<<BB, 256, 0, stream>>>(mu, xmean, klp);
    // 8) mid_bf = bf16((attn @ enc_values) * sqrt(S))   [64-tile, 512 blocks]
    k_gemm64<3><<<dim3(16, 2, BB), 256, 0, stream>>>(
        attnb, valsT, nullptr, nullptr, nullptr, mid_bf, TT, EE, SS, SQRT_S);
    // 9) out = (mid @ W_out^T + b_out + x) * sqrt(.5)   [64-tile, 512 blocks]
    k_gemm64<1><<<dim3(256, 2, 1), 256, 0, stream>>>(
        mid_bf, Wout_bf, b_out, x, outp, nullptr, BB * TT, CC, CC, 1.0f);
}

// Round 4
// 468.295 us; speedup vs baseline: 1.2231x; 1.0921x over previous
//
#include <hip/hip_runtime.h>
#include <math.h>

#define BB 16
#define TT 1024
#define SS 2048
#define CC 256
#define EE 256
#define NSUB 103        // (SS-1)/STRIDE + 1
#define MAXS 20
#define STRIDE_ 20
#define XCH 32          // t-chunks for xmean partials (TT/XCH = 32 rows each)

static constexpr float RSQRT2  = 0.70710678118654752440f;   // sqrt(0.5)
static constexpr float SQRT_S  = 45.25483399593904f;        // s*sqrt(1/s) = sqrt(2048)
static constexpr float GNORM   = 0.13298076013381093f;      // 1/(sqrt(2*pi)*3)
static constexpr float INV2S2  = 0.055555555555555555f;     // 1/(2*sigma^2)

typedef __attribute__((ext_vector_type(8))) __bf16 bf16x8;
typedef __attribute__((ext_vector_type(4))) float  f32x4;

__device__ __forceinline__ float wave_sum(float v) {
    #pragma unroll
    for (int o = 32; o; o >>= 1) v += __shfl_down(v, o);
    return v;
}
__device__ __forceinline__ float wave_max(float v) {
    #pragma unroll
    for (int o = 32; o; o >>= 1) v = fmaxf(v, __shfl_down(v, o));
    return v;
}
__device__ __forceinline__ unsigned short f2bf(float f) {   // RNE
    unsigned int u = __float_as_uint(f);
    u = (u + 0x7FFFu + ((u >> 16) & 1u)) >> 16;
    return (unsigned short)u;
}
__device__ __forceinline__ float bf2f(unsigned short s) {
    return __uint_as_float(((unsigned int)s) << 16);
}

#define GLD_LDS16(g, l) __builtin_amdgcn_global_load_lds(                      \
    (const __attribute__((address_space(1))) void*)(g),                        \
    (__attribute__((address_space(3))) void*)(l), 16, 0, 0)

// fp32 -> bf16 cast, 4 elems/thread
__global__ __launch_bounds__(256) void k_cast_bf16(const float* __restrict__ in,
                                                   unsigned short* __restrict__ out, int n4)
{
    const int i = blockIdx.x * 256 + threadIdx.x;
    if (i < n4) {
        const float4 v = reinterpret_cast<const float4*>(in)[i];
        union { unsigned short u[4]; unsigned long long v8; } pk;
        pk.u[0] = f2bf(v.x); pk.u[1] = f2bf(v.y);
        pk.u[2] = f2bf(v.z); pk.u[3] = f2bf(v.w);
        reinterpret_cast<unsigned long long*>(out)[i] = pk.v8;
    }
}

// fp32 [Bz][R][Cc] -> bf16 [Bz][Cc][R] transpose. grid (R/64, Cc/64, Bz), 256 thr
__global__ __launch_bounds__(256) void k_transpose_bf16(
    const float* __restrict__ in, unsigned short* __restrict__ out, int R, int Cc)
{
    __shared__ float t[64][65];
    const int b = blockIdx.z;
    const int r0 = blockIdx.x * 64, c0 = blockIdx.y * 64;
    const float* ip = in + (size_t)b * R * Cc;
    unsigned short* op = out + (size_t)b * R * Cc;
    const int tx = threadIdx.x & 63, ty = threadIdx.x >> 6;  // ty in [0,4)
    #pragma unroll
    for (int i = 0; i < 16; ++i)
        t[ty + 4 * i][tx] = ip[(size_t)(r0 + ty + 4 * i) * Cc + c0 + tx];
    __syncthreads();
    #pragma unroll
    for (int i = 0; i < 16; ++i)
        op[(size_t)(c0 + ty + 4 * i) * R + r0 + tx] = f2bf(t[tx][ty + 4 * i]);
}

// ---------------------------------------------------------------------------
// Unified bf16 MFMA GEMM: A [Bz][M][K] bf16, Bt [Bz][N][K] bf16 (B^T),
// O[m,n] = epilogue(sum_k A[m,k]*Bt[n,k]).  BK=64, XOR-swizzled LDS:
// swizzle applied on the GLOBAL source column so the global_load_lds dest
// stays linear (wave-uniform base + lane*16 — HW requirement); reads apply
// the same XOR: LDS[row][c] = global[row][c ^ ((row&7)<<4)].
// 4 waves in a 2(M)x2(N) grid; per-wave sub-tile (BM/2)x(BN/2).
// MODE 0: Of = acc*scale
// MODE 1: Of = (acc + bias[n] + add[m,n])*RSQRT2
// MODE 2: Ob = bf16((acc + bias[n] + add[m,n])*RSQRT2)
// MODE 3: Ob = bf16(acc*scale)
// ---------------------------------------------------------------------------
template<int BM, int BN, int MODE>
__global__ __launch_bounds__(256) void k_gemm(
    const unsigned short* __restrict__ Abase,
    const unsigned short* __restrict__ Btbase,
    const float* __restrict__ bias, const float* __restrict__ add,
    float* __restrict__ Obase, unsigned short* __restrict__ Obbase,
    int M, int Nn, int K, float scale)
{
    constexpr int BK = 64;                    // k elems per step (128B rows)
    constexpr int AR = BM / 32;               // 4KB staging rounds for A
    constexpr int BR = BN / 32;
    constexpr int WM = BM / 2, WN = BN / 2;   // per-wave sub-tile
    constexpr int MI = WM / 16, NJ = WN / 16; // fragment repeats

    __shared__ unsigned short As[BM * BK];
    __shared__ unsigned short Bs[BN * BK];

    const int b  = blockIdx.z;
    const int m0 = blockIdx.x * BM;
    const int n0 = blockIdx.y * BN;
    const unsigned short* A  = Abase  + (size_t)b * M  * K;
    const unsigned short* Bt = Btbase + (size_t)b * Nn * K;

    const int tid  = threadIdx.x;
    const int w    = tid >> 6;
    const int lane = tid & 63;
    const int wm   = w & 1, wn = w >> 1;

    // staging: 8 threads per 128B row; round p covers rows [p*32, p*32+32).
    // Wave w's 64 lanes cover rows p*32 + w*8 .. +8 (8 lanes per row).
    // LDS dest is LINEAR: wave-uniform base (As + p*4096B + w*1024B), HW adds
    // lane*16B -> LDS byte tid*16.  Global source column is pre-swizzled so
    // LDS (row, c) holds global element (row, c ^ ((row&7)<<4)).
    const int sr  = tid >> 3;                                   // row 0..31
    const int skb = ((tid & 7) << 4) ^ ((sr & 7) << 4);         // byte col [0,128)
    const unsigned short* ga[AR];
    const unsigned short* gb[BR];
    #pragma unroll
    for (int p = 0; p < AR; ++p)
        ga[p] = A + (size_t)(m0 + p * 32 + sr) * K + (skb >> 1);
    #pragma unroll
    for (int p = 0; p < BR; ++p)
        gb[p] = Bt + (size_t)(n0 + p * 32 + sr) * K + (skb >> 1);

    const int fr = lane & 15;            // m/n within a 16-tile
    const int qb = (lane >> 4) << 4;     // byte offset of this lane's k-quad

    f32x4 acc[MI][NJ];
    #pragma unroll
    for (int i = 0; i < MI; ++i)
        #pragma unroll
        for (int j = 0; j < NJ; ++j)
            acc[i][j] = (f32x4){0.f, 0.f, 0.f, 0.f};

    for (int k0 = 0; k0 < K; k0 += BK) {
        #pragma unroll
        for (int p = 0; p < AR; ++p) GLD_LDS16(ga[p], As + p * 2048 + w * 512);
        #pragma unroll
        for (int p = 0; p < BR; ++p) GLD_LDS16(gb[p], Bs + p * 2048 + w * 512);
        #pragma unroll
        for (int p = 0; p < AR; ++p) ga[p] += BK;
        #pragma unroll
        for (int p = 0; p < BR; ++p) gb[p] += BK;
        __syncthreads();
        #pragma unroll
        for (int c = 0; c < 2; ++c) {     // two 32-k chunks of the 64-k step
            bf16x8 af[MI], bf[NJ];
            #pragma unroll
            for (int i = 0; i < MI; ++i) {
                const int row = wm * WM + i * 16 + fr;
                const int byt = row * 128 + ((c * 64 + qb) ^ ((row & 7) << 4));
                af[i] = *reinterpret_cast<const bf16x8*>(
                            reinterpret_cast<const char*>(As) + byt);
            }
            #pragma unroll
            for (int j = 0; j < NJ; ++j) {
                const int row = wn * WN + j * 16 + fr;
                const int byt = row * 128 + ((c * 64 + qb) ^ ((row & 7) << 4));
                bf[j] = *reinterpret_cast<const bf16x8*>(
                            reinterpret_cast<const char*>(Bs) + byt);
            }
            #pragma unroll
            for (int i = 0; i < MI; ++i)
                #pragma unroll
                for (int j = 0; j < NJ; ++j)
                    acc[i][j] = __builtin_amdgcn_mfma_f32_16x16x32_bf16(af[i], bf[j], acc[i][j], 0, 0, 0);
        }
        __syncthreads();
    }

    // C/D layout: col = lane&15, row = (lane>>4)*4 + reg   [m89-verified]
    float* Of = (MODE == 0 || MODE == 1) ? Obase + (size_t)b * M * Nn : nullptr;
    unsigned short* Ob = (MODE == 2 || MODE == 3) ? Obbase + (size_t)b * M * Nn : nullptr;
    const int rb = (lane >> 4) * 4;
    #pragma unroll
    for (int i = 0; i < MI; ++i)
        #pragma unroll
        for (int j = 0; j < NJ; ++j) {
            const int n = n0 + wn * WN + j * 16 + fr;
            #pragma unroll
            for (int r2 = 0; r2 < 4; ++r2) {
                const int m = m0 + wm * WM + i * 16 + rb + r2;
                const size_t idx = (size_t)m * Nn + n;
                if (MODE == 0) {
                    Of[idx] = acc[i][j][r2] * scale;
                } else if (MODE == 1) {
                    Of[idx] = (acc[i][j][r2] + bias[n] + add[idx]) * RSQRT2;
                } else if (MODE == 2) {
                    Ob[idx] = f2bf((acc[i][j][r2] + bias[n] + add[idx]) * RSQRT2);
                } else {
                    Ob[idx] = f2bf(acc[i][j][r2] * scale);
                }
            }
        }
}

// Row softmax over S=2048. Input: bf16 scores in attnb. Output: fp32 attn
// (required output) + normalized bf16 back into attnb IN PLACE.
__global__ __launch_bounds__(256) void k_softmax(float* __restrict__ attn,
                                                 unsigned short* __restrict__ attnb)
{
    float* p = attn + (size_t)blockIdx.x * SS;
    unsigned short* pb = attnb + (size_t)blockIdx.x * SS;
    const int tid = threadIdx.x;
    __shared__ float w[4];
    union { unsigned short u[8]; uint4 v4; } in;
    in.v4 = *reinterpret_cast<const uint4*>(&pb[tid * 8]);
    float v[8];
    #pragma unroll
    for (int i = 0; i < 8; ++i) v[i] = bf2f(in.u[i]);
    float mx = -INFINITY;
    #pragma unroll
    for (int i = 0; i < 8; ++i) mx = fmaxf(mx, v[i]);
    float wm = wave_max(mx);
    if ((tid & 63) == 0) w[tid >> 6] = wm;
    __syncthreads();
    const float m = fmaxf(fmaxf(w[0], w[1]), fmaxf(w[2], w[3]));
    float s = 0.f;
    #pragma unroll
    for (int i = 0; i < 8; ++i) { v[i] = expf(v[i] - m); s += v[i]; }
    __syncthreads();
    float wsv = wave_sum(s);
    if ((tid & 63) == 0) w[tid >> 6] = wsv;
    __syncthreads();
    const float inv = 1.0f / (w[0] + w[1] + w[2] + w[3]);
    float4 o0, o1;
    o0.x = v[0] * inv; o0.y = v[1] * inv; o0.z = v[2] * inv; o0.w = v[3] * inv;
    o1.x = v[4] * inv; o1.y = v[5] * inv; o1.z = v[6] * inv; o1.w = v[7] * inv;
    *reinterpret_cast<float4*>(&p[tid * 8])     = o0;
    *reinterpret_cast<float4*>(&p[tid * 8 + 4]) = o1;
    union { unsigned short u[8]; uint4 v4; } pk;
    pk.u[0] = f2bf(o0.x); pk.u[1] = f2bf(o0.y); pk.u[2] = f2bf(o0.z); pk.u[3] = f2bf(o0.w);
    pk.u[4] = f2bf(o1.x); pk.u[5] = f2bf(o1.y); pk.u[6] = f2bf(o1.z); pk.u[7] = f2bf(o1.w);
    *reinterpret_cast<uint4*>(&pb[tid * 8]) = pk.v4;
}

// Partial t-sums of attn: part[b][c][s] = sum_{t in chunk c} attnb[b][t][s].
// grid (XCH, B), 256 thr; fully-coalesced uint4 row reads.
__global__ __launch_bounds__(256) void k_xmean_part(const unsigned short* __restrict__ attnb,
                                                    float* __restrict__ part)
{
    const int c = blockIdx.x, b = blockIdx.y;
    const unsigned short* p = attnb + ((size_t)b * TT + (size_t)c * (TT / XCH)) * SS
                              + threadIdx.x * 8;
    float acc[8] = {0.f, 0.f, 0.f, 0.f, 0.f, 0.f, 0.f, 0.f};
    #pragma unroll 8
    for (int t = 0; t < TT / XCH; ++t) {
        union { unsigned short u[8]; uint4 v4; } ld;
        ld.v4 = *reinterpret_cast<const uint4*>(p + (size_t)t * SS);
        #pragma unroll
        for (int i = 0; i < 8; ++i) acc[i] += bf2f(ld.u[i]);
    }
    float* o = part + ((size_t)b * XCH + c) * SS + threadIdx.x * 8;
    #pragma unroll
    for (int i = 0; i < 8; ++i) o[i] = acc[i];
}

// ns[b,n,:] = enc_values[b, n*STRIDE, :]/||.||;  aa[b,n] = xmean[b, n*STRIDE]
// (aa summed inline from the XCH partials). Also zeroes klp.
__global__ __launch_bounds__(256) void k_ns(const float* __restrict__ ev,
                                            const float* __restrict__ part,
                                            float* __restrict__ ns, float* __restrict__ aa,
                                            float* __restrict__ klp)
{
    const int n = blockIdx.x, b = blockIdx.y;
    const int tid = threadIdx.x;
    if (n == 0 && b == 0 && tid == 0) klp[0] = 0.0f;
    const float* rowp = ev + ((size_t)b * SS + (size_t)n * STRIDE_) * EE;
    const float v = rowp[tid];
    __shared__ float w[4];
    float r = wave_sum(v * v);
    if ((tid & 63) == 0) w[tid >> 6] = r;
    float pv = (tid < XCH) ? part[((size_t)b * XCH + tid) * SS + n * STRIDE_] : 0.f;
    float psum = wave_sum(pv);          // valid in lane 0 of wave 0
    __syncthreads();
    const float nrm = sqrtf(w[0] + w[1] + w[2] + w[3]);
    ns[((size_t)b * NSUB + n) * EE + tid] = v / nrm;
    if (tid == 0) aa[b * NSUB + n] = psum * (1.0f / TT);
}

// L[b,i,j] = (aa_i*aa_j) * dot(ns_i, ns_j).  grid (N, B), 128 thr
__global__ __launch_bounds__(128) void k_L(const float* __restrict__ ns,
                                           const float* __restrict__ aa,
                                           float* __restrict__ Lm)
{
    const int i = blockIdx.x, b = blockIdx.y;
    const int tid = threadIdx.x;
    __shared__ float nsi[EE];
    nsi[tid]       = ns[((size_t)b * NSUB + i) * EE + tid];
    nsi[tid + 128] = ns[((size_t)b * NSUB + i) * EE + tid + 128];
    __syncthreads();
    const float ai = aa[b * NSUB + i];
    for (int j = tid; j < NSUB; j += 128) {
        const float* rj = ns + ((size_t)b * NSUB + j) * EE;
        float d = 0.f;
        #pragma unroll 4
        for (int e = 0; e < EE; ++e) d += nsi[e] * rj[e];
        Lm[((size_t)b * NSUB + i) * NSUB + j] = d * ai * aa[b * NSUB + j];
    }
}

// Greedy MAP DPP (Cholesky) — one block (128 thr = 2 waves) per batch.
__global__ __launch_bounds__(128) void k_bfgm(const float* __restrict__ Lm,
                                              float* __restrict__ mu)
{
    const int b = blockIdx.x;
    const int tid = threadIdx.x;
    const float* L = Lm + (size_t)b * NSUB * NSUB;
    __shared__ float D[128], mask[128], Cm[128][MAXS], cj[MAXS];
    __shared__ float rv[2];
    __shared__ int   ri[2];
    __shared__ int   Jsh;
    const bool act = tid < NSUB;
    D[tid]    = act ? L[(size_t)tid * NSUB + tid] : 0.0f;
    mask[tid] = act ? 1.0f : 0.0f;
    #pragma unroll
    for (int k = 0; k < MAXS; ++k) Cm[tid][k] = 0.0f;
    __syncthreads();

    auto argmax_step = [&](int t) {
        float key = act ? logf(D[tid] * mask[tid]) : -INFINITY;
        if (isnan(key)) key = INFINITY;   // numpy argmax: NaN wins
        float v = key; int idx = tid;
        #pragma unroll
        for (int o = 32; o; o >>= 1) {
            float ov = __shfl_down(v, o); int oi = __shfl_down(idx, o);
            if (ov > v || (ov == v && oi < idx)) { v = ov; idx = oi; }
        }
        if ((tid & 63) == 0) { rv[tid >> 6] = v; ri[tid >> 6] = idx; }
        __syncthreads();
        if (tid == 0) {
            const int J = (rv[1] > rv[0] || (rv[1] == rv[0] && ri[1] < ri[0])) ? ri[1] : ri[0];
            Jsh = J; mask[J] = 0.0f; mu[b * MAXS + t] = (float)J;
        }
        __syncthreads();
    };

    argmax_step(0);
    for (int t = 1; t < MAXS; ++t) {
        if (tid < MAXS) cj[tid] = Cm[Jsh][tid];
        __syncthreads();
        const int J = Jsh;
        const float dj = D[J];
        float e = 0.0f;
        if (act) {
            const float Ljn = L[(size_t)J * NSUB + tid];
            float cd = 0.f;
            #pragma unroll
            for (int k = 0; k < MAXS; ++k) cd += Cm[tid][k] * cj[k];
            e = (Ljn - cd) / dj * mask[tid];
        }
        Cm[tid][t] = e;
        D[tid] -= e * e;
        __syncthreads();
        argmax_step(t);
    }
}

// dist computed in registers, consumed into KL with xmean summed inline from
// partials:  klp -= sum_s xm*(log xm - dist).  grid B, 256 thr.
__global__ __launch_bounds__(256) void k_dist_kl(const float* __restrict__ mu,
                                                 const float* __restrict__ part,
                                                 float* __restrict__ outkl)
{
    const int b = blockIdx.x;
    const int tid = threadIdx.x;
    __shared__ float mus[MAXS];
    __shared__ float w[4];
    if (tid < MAXS) mus[tid] = mu[b * MAXS + tid];
    __syncthreads();
    float xm[8];
    #pragma unroll
    for (int i = 0; i < 8; ++i) {
        float s = 0.f;
        #pragma unroll 8
        for (int c2 = 0; c2 < XCH; ++c2)
            s += part[((size_t)b * XCH + c2) * SS + tid + (i << 8)];
        xm[i] = s * (1.0f / TT);
    }
    float g[8];
    float mx = -INFINITY;
    #pragma unroll
    for (int i = 0; i < 8; ++i) {
        const float s = (float)(tid + (i << 8));
        float acc = 0.f;
        #pragma unroll
        for (int m = 0; m < MAXS; ++m) { const float z = s - mus[m]; acc += expf(-(z * z) * INV2S2); }
        g[i] = acc * GNORM;
        mx = fmaxf(mx, g[i]);
    }
    float wm = wave_max(mx);
    if ((tid & 63) == 0) w[tid >> 6] = wm;
    __syncthreads();
    const float m = fmaxf(fmaxf(w[0], w[1]), fmaxf(w[2], w[3]));
    float sum = 0.f;
    #pragma unroll
    for (int i = 0; i < 8; ++i) { g[i] = expf(g[i] - m); sum += g[i]; }
    __syncthreads();
    float wsv = wave_sum(sum);
    if ((tid & 63) == 0) w[tid >> 6] = wsv;
    __syncthreads();
    const float inv = 1.0f / (w[0] + w[1] + w[2] + w[3]);
    float acc2 = 0.f;
    #pragma unroll
    for (int i = 0; i < 8; ++i)
        acc2 += xm[i] * (logf(xm[i]) - g[i] * inv);
    __syncthreads();
    float wp = wave_sum(acc2);
    if ((tid & 63) == 0) w[tid >> 6] = wp;
    __syncthreads();
    if (tid == 0) atomicAdd(outkl, -(w[0] + w[1] + w[2] + w[3]));
}

extern "C" void kernel_launch(void* const* d_in, const int* in_sizes, int n_in,
                              void* d_out, int out_size, void* d_ws, size_t ws_size,
                              hipStream_t stream)
{
    const float* x     = (const float*)d_in[0];   // (B,T,C)
    const float* te    = (const float*)d_in[1];   // (B,T,E)
    const float* keys  = (const float*)d_in[2];   // (B,E,S)
    const float* vals  = (const float*)d_in[3];   // (B,S,E)
    const float* W_in  = (const float*)d_in[4];   // (E,C)
    const float* b_in  = (const float*)d_in[5];   // (E)
    const float* W_out = (const float*)d_in[6];   // (C,E)
    const float* b_out = (const float*)d_in[7];   // (C)

    float* outp = (float*)d_out;                       // (B,T,C)
    float* attn = outp + (size_t)BB * TT * CC;         // (B,T,S) fp32
    float* klp  = attn + (size_t)BB * TT * SS;         // scalar

    // workspace
    unsigned short* X       = (unsigned short*)d_ws;
    unsigned short* x_bf    = X;                                       // B*T*C
    unsigned short* Win_bf  = x_bf   + (size_t)BB * TT * CC;           // E*C
    unsigned short* Wout_bf = Win_bf + (size_t)EE * CC;                // C*E
    unsigned short* h_bf    = Wout_bf+ (size_t)CC * EE;                // B*T*E
    unsigned short* keysT   = h_bf   + (size_t)BB * TT * EE;           // B*S*E
    unsigned short* valsT   = keysT  + (size_t)BB * SS * EE;           // B*E*S
    unsigned short* attnb   = valsT  + (size_t)BB * EE * SS;           // B*T*S (scores, then attn)
    unsigned short* mid_bf  = attnb  + (size_t)BB * TT * SS;           // B*T*E
    float* fws   = (float*)(mid_bf + (size_t)BB * TT * EE + 8);
    float* part  = fws;                                  // (B,XCH,S)
    float* ns    = part  + (size_t)BB * XCH * SS;        // (B,N,E)
    float* aa    = ns    + (size_t)BB * NSUB * EE;       // (B,N)
    float* Lm    = aa    + (size_t)BB * NSUB;            // (B,N,N)
    float* mu    = Lm    + (size_t)BB * NSUB * NSUB;     // (B,MAXS)

    // casts
    k_cast_bf16<<<(BB * TT * CC / 4 + 255) / 256, 256, 0, stream>>>(x, x_bf, BB * TT * CC / 4);
    k_cast_bf16<<<(EE * CC / 4 + 255) / 256, 256, 0, stream>>>(W_in, Win_bf, EE * CC / 4);
    k_cast_bf16<<<(CC * EE / 4 + 255) / 256, 256, 0, stream>>>(W_out, Wout_bf, CC * EE / 4);
    // 1) h_bf = bf16((x @ W_in^T + b_in + te) * sqrt(.5))   [64x128, 512 blocks]
    k_gemm<64, 128, 2><<<dim3(256, 2, 1), 256, 0, stream>>>(
        x_bf, Win_bf, b_in, te, nullptr, h_bf, BB * TT, CC, CC, 1.0f);
    // 2) keysT[b,s,e] = keys[b,e,s] (bf16)
    k_transpose_bf16<<<dim3(4, 32, BB), 256, 0, stream>>>(keys, keysT, EE, SS);
    // 3) scores (bf16) -> attnb   [128x128, 2048 blocks]
    k_gemm<128, 128, 3><<<dim3(8, 16, BB), 256, 0, stream>>>(
        h_bf, keysT, nullptr, nullptr, nullptr, attnb, TT, SS, EE, 1.0f);
    // 4) valsT[b,e,s] = vals[b,s,e] (bf16)
    k_transpose_bf16<<<dim3(32, 4, BB), 256, 0, stream>>>(vals, valsT, SS, EE);
    // 5) softmax: attnb(scores bf16) -> attn fp32 (output) + attnb bf16 in place
    k_softmax<<<BB * TT, 256, 0, stream>>>(attn, attnb);
    // 6) x_mean partials from bf16 attn   [512 blocks]
    k_xmean_part<<<dim3(XCH, BB), 256, 0, stream>>>(attnb, part);
    // 7) DPP chain (k_ns also zeroes klp for the k_dist_kl atomics)
    k_ns<<<dim3(NSUB, BB), 256, 0, stream>>>(vals, part, ns, aa, klp);
    k_L<<<dim3(NSUB, BB), 128, 0, stream>>>(ns, aa, Lm);
    k_bfgm<<<BB, 128, 0, stream>>>(Lm, mu);
    k_dist_kl<<<BB, 256, 0, stream>>>(mu, part, klp);
    // 8) mid_bf = bf16((attn @ enc_values) * sqrt(S))   [64x128, 512 blocks]
    k_gemm<64, 128, 3><<<dim3(16, 2, BB), 256, 0, stream>>>(
        attnb, valsT, nullptr, nullptr, nullptr, mid_bf, TT, EE, SS, SQRT_S);
    // 9) out = (mid @ W_out^T + b_out + x) * sqrt(.5)   [64x128, 512 blocks]
    k_gemm<64, 128, 1><<<dim3(256, 2, 1), 256, 0, stream>>>(
        mid_bf, Wout_bf, b_out, x, outp, nullptr, BB * TT, CC, CC, 1.0f);
}

// Round 5
// 460.389 us; speedup vs baseline: 1.2441x; 1.0172x over previous
//
#include <hip/hip_runtime.h>
#include <math.h>

#define BB 16
#define TT 1024
#define SS 2048
#define CC 256
#define EE 256
#define NSUB 103        // (SS-1)/STRIDE + 1
#define MAXS 20
#define STRIDE_ 20
#define XCH 32          // t-chunks for xmean partials (TT/XCH = 32 rows each)

static constexpr float RSQRT2  = 0.70710678118654752440f;   // sqrt(0.5)
static constexpr float SQRT_S  = 45.25483399593904f;        // s*sqrt(1/s) = sqrt(2048)
static constexpr float GNORM   = 0.13298076013381093f;      // 1/(sqrt(2*pi)*3)
static constexpr float INV2S2  = 0.055555555555555555f;     // 1/(2*sigma^2)

typedef __attribute__((ext_vector_type(8))) __bf16 bf16x8;
typedef __attribute__((ext_vector_type(4))) float  f32x4;

__device__ __forceinline__ float wave_sum(float v) {
    #pragma unroll
    for (int o = 32; o; o >>= 1) v += __shfl_down(v, o);
    return v;
}
__device__ __forceinline__ float wave_max(float v) {
    #pragma unroll
    for (int o = 32; o; o >>= 1) v = fmaxf(v, __shfl_down(v, o));
    return v;
}
__device__ __forceinline__ unsigned short f2bf(float f) {   // RNE
    unsigned int u = __float_as_uint(f);
    u = (u + 0x7FFFu + ((u >> 16) & 1u)) >> 16;
    return (unsigned short)u;
}
__device__ __forceinline__ float bf2f(unsigned short s) {
    return __uint_as_float(((unsigned int)s) << 16);
}

#define GLD_LDS16(g, l) __builtin_amdgcn_global_load_lds(                      \
    (const __attribute__((address_space(1))) void*)(g),                        \
    (__attribute__((address_space(3))) void*)(l), 16, 0, 0)

// fp32 -> bf16 cast over three disjoint buffers in one launch.
__global__ __launch_bounds__(256) void k_cast3(
    const float* __restrict__ a,  unsigned short* __restrict__ oa, int na,
    const float* __restrict__ b2, unsigned short* __restrict__ ob, int nb,
    const float* __restrict__ c2, unsigned short* __restrict__ oc, int nc)
{
    int i = blockIdx.x * 256 + threadIdx.x;
    const float* in; unsigned short* out;
    if (i < na)                { in = a;  out = oa; }
    else if (i < na + nb)      { in = b2; out = ob; i -= na; }
    else if (i < na + nb + nc) { in = c2; out = oc; i -= na + nb; }
    else return;
    const float4 v = reinterpret_cast<const float4*>(in)[i];
    union { unsigned short u[4]; unsigned long long v8; } pk;
    pk.u[0] = f2bf(v.x); pk.u[1] = f2bf(v.y);
    pk.u[2] = f2bf(v.z); pk.u[3] = f2bf(v.w);
    reinterpret_cast<unsigned long long*>(out)[i] = pk.v8;
}

// fp32 [Bz][R][Cc] -> bf16 [Bz][Cc][R] transpose. grid (R/64, Cc/64, Bz), 256 thr
__global__ __launch_bounds__(256) void k_transpose_bf16(
    const float* __restrict__ in, unsigned short* __restrict__ out, int R, int Cc)
{
    __shared__ float t[64][65];
    const int b = blockIdx.z;
    const int r0 = blockIdx.x * 64, c0 = blockIdx.y * 64;
    const float* ip = in + (size_t)b * R * Cc;
    unsigned short* op = out + (size_t)b * R * Cc;
    const int tx = threadIdx.x & 63, ty = threadIdx.x >> 6;  // ty in [0,4)
    #pragma unroll
    for (int i = 0; i < 16; ++i)
        t[ty + 4 * i][tx] = ip[(size_t)(r0 + ty + 4 * i) * Cc + c0 + tx];
    __syncthreads();
    #pragma unroll
    for (int i = 0; i < 16; ++i)
        op[(size_t)(c0 + ty + 4 * i) * R + r0 + tx] = f2bf(t[tx][ty + 4 * i]);
}

// ---------------------------------------------------------------------------
// Unified bf16 MFMA GEMM: A [Bz][M][K] bf16, Bt [Bz][N][K] bf16 (B^T),
// O[m,n] = epilogue(sum_k A[m,k]*Bt[n,k]).  BK=64, XOR-swizzled LDS
// (pre-swizzled global source column, linear global_load_lds dest; reads
// apply the same XOR: LDS[row][c] = global[row][c ^ ((row&7)<<4)]).
// XCD-chunked bijective blockIdx swizzle (nwg % 8 == 0 for all our grids).
// 4 waves in a 2(M)x2(N) grid; per-wave sub-tile (BM/2)x(BN/2).
// MODE 0: Of = acc*scale
// MODE 1: Of = (acc + bias[n] + add[m,n])*RSQRT2
// MODE 2: Ob = bf16((acc + bias[n] + add[m,n])*RSQRT2)
// MODE 3: Ob = bf16(acc*scale)
// ---------------------------------------------------------------------------
template<int BM, int BN, int MODE>
__global__ __launch_bounds__(256) void k_gemm(
    const unsigned short* __restrict__ Abase,
    const unsigned short* __restrict__ Btbase,
    const float* __restrict__ bias, const float* __restrict__ add,
    float* __restrict__ Obase, unsigned short* __restrict__ Obbase,
    int M, int Nn, int K, float scale)
{
    constexpr int BK = 64;                    // k elems per step (128B rows)
    constexpr int AR = BM / 32;               // 4KB staging rounds for A
    constexpr int BR = BN / 32;
    constexpr int WM = BM / 2, WN = BN / 2;   // per-wave sub-tile
    constexpr int MI = WM / 16, NJ = WN / 16; // fragment repeats

    __shared__ unsigned short As[BM * BK];
    __shared__ unsigned short Bs[BN * BK];

    // XCD-chunked swizzle: hardware id H (round-robin over 8 XCDs) -> logical
    // id l such that logically-consecutive tiles (sharing operand panels)
    // land on the same XCD. Bijective when nwg % 8 == 0.
    const int nwg = gridDim.x * gridDim.y * gridDim.z;
    int l = blockIdx.x + gridDim.x * (blockIdx.y + gridDim.y * blockIdx.z);
    if ((nwg & 7) == 0) l = (l & 7) * (nwg >> 3) + (l >> 3);
    const int bx = l % gridDim.x; l /= gridDim.x;
    const int by = l % gridDim.y;
    const int b  = l / gridDim.y;

    const int m0 = bx * BM;
    const int n0 = by * BN;
    const unsigned short* A  = Abase  + (size_t)b * M  * K;
    const unsigned short* Bt = Btbase + (size_t)b * Nn * K;

    const int tid  = threadIdx.x;
    const int w    = tid >> 6;
    const int lane = tid & 63;
    const int wm   = w & 1, wn = w >> 1;

    // staging: 8 threads per 128B row; round p covers rows [p*32, p*32+32).
    // LDS dest is LINEAR: wave-uniform base, HW adds lane*16B. Global source
    // column pre-swizzled: LDS (row,c) = global (row, c ^ ((row&7)<<4)).
    const int sr  = tid >> 3;                                   // row 0..31
    const int skb = ((tid & 7) << 4) ^ ((sr & 7) << 4);         // byte col [0,128)
    const unsigned short* ga[AR];
    const unsigned short* gb[BR];
    #pragma unroll
    for (int p = 0; p < AR; ++p)
        ga[p] = A + (size_t)(m0 + p * 32 + sr) * K + (skb >> 1);
    #pragma unroll
    for (int p = 0; p < BR; ++p)
        gb[p] = Bt + (size_t)(n0 + p * 32 + sr) * K + (skb >> 1);

    const int fr = lane & 15;            // m/n within a 16-tile
    const int qb = (lane >> 4) << 4;     // byte offset of this lane's k-quad

    f32x4 acc[MI][NJ];
    #pragma unroll
    for (int i = 0; i < MI; ++i)
        #pragma unroll
        for (int j = 0; j < NJ; ++j)
            acc[i][j] = (f32x4){0.f, 0.f, 0.f, 0.f};

    for (int k0 = 0; k0 < K; k0 += BK) {
        #pragma unroll
        for (int p = 0; p < AR; ++p) GLD_LDS16(ga[p], As + p * 2048 + w * 512);
        #pragma unroll
        for (int p = 0; p < BR; ++p) GLD_LDS16(gb[p], Bs + p * 2048 + w * 512);
        #pragma unroll
        for (int p = 0; p < AR; ++p) ga[p] += BK;
        #pragma unroll
        for (int p = 0; p < BR; ++p) gb[p] += BK;
        __syncthreads();
        #pragma unroll
        for (int c = 0; c < 2; ++c) {     // two 32-k chunks of the 64-k step
            bf16x8 af[MI], bf[NJ];
            #pragma unroll
            for (int i = 0; i < MI; ++i) {
                const int row = wm * WM + i * 16 + fr;
                const int byt = row * 128 + ((c * 64 + qb) ^ ((row & 7) << 4));
                af[i] = *reinterpret_cast<const bf16x8*>(
                            reinterpret_cast<const char*>(As) + byt);
            }
            #pragma unroll
            for (int j = 0; j < NJ; ++j) {
                const int row = wn * WN + j * 16 + fr;
                const int byt = row * 128 + ((c * 64 + qb) ^ ((row & 7) << 4));
                bf[j] = *reinterpret_cast<const bf16x8*>(
                            reinterpret_cast<const char*>(Bs) + byt);
            }
            #pragma unroll
            for (int i = 0; i < MI; ++i)
                #pragma unroll
                for (int j = 0; j < NJ; ++j)
                    acc[i][j] = __builtin_amdgcn_mfma_f32_16x16x32_bf16(af[i], bf[j], acc[i][j], 0, 0, 0);
        }
        __syncthreads();
    }

    // C/D layout: col = lane&15, row = (lane>>4)*4 + reg   [m89-verified]
    float* Of = (MODE == 0 || MODE == 1) ? Obase + (size_t)b * M * Nn : nullptr;
    unsigned short* Ob = (MODE == 2 || MODE == 3) ? Obbase + (size_t)b * M * Nn : nullptr;
    const int rb = (lane >> 4) * 4;
    #pragma unroll
    for (int i = 0; i < MI; ++i)
        #pragma unroll
        for (int j = 0; j < NJ; ++j) {
            const int n = n0 + wn * WN + j * 16 + fr;
            #pragma unroll
            for (int r2 = 0; r2 < 4; ++r2) {
                const int m = m0 + wm * WM + i * 16 + rb + r2;
                const size_t idx = (size_t)m * Nn + n;
                if (MODE == 0) {
                    Of[idx] = acc[i][j][r2] * scale;
                } else if (MODE == 1) {
                    Of[idx] = (acc[i][j][r2] + bias[n] + add[idx]) * RSQRT2;
                } else if (MODE == 2) {
                    Ob[idx] = f2bf((acc[i][j][r2] + bias[n] + add[idx]) * RSQRT2);
                } else {
                    Ob[idx] = f2bf(acc[i][j][r2] * scale);
                }
            }
        }
}

// Row softmax over S=2048. Input: bf16 scores in attnb. Output: fp32 attn
// (required output) + normalized bf16 back into attnb IN PLACE.
__global__ __launch_bounds__(256) void k_softmax(float* __restrict__ attn,
                                                 unsigned short* __restrict__ attnb)
{
    float* p = attn + (size_t)blockIdx.x * SS;
    unsigned short* pb = attnb + (size_t)blockIdx.x * SS;
    const int tid = threadIdx.x;
    __shared__ float w[4];
    union { unsigned short u[8]; uint4 v4; } in;
    in.v4 = *reinterpret_cast<const uint4*>(&pb[tid * 8]);
    float v[8];
    #pragma unroll
    for (int i = 0; i < 8; ++i) v[i] = bf2f(in.u[i]);
    float mx = -INFINITY;
    #pragma unroll
    for (int i = 0; i < 8; ++i) mx = fmaxf(mx, v[i]);
    float wm = wave_max(mx);
    if ((tid & 63) == 0) w[tid >> 6] = wm;
    __syncthreads();
    const float m = fmaxf(fmaxf(w[0], w[1]), fmaxf(w[2], w[3]));
    float s = 0.f;
    #pragma unroll
    for (int i = 0; i < 8; ++i) { v[i] = expf(v[i] - m); s += v[i]; }
    __syncthreads();
    float wsv = wave_sum(s);
    if ((tid & 63) == 0) w[tid >> 6] = wsv;
    __syncthreads();
    const float inv = 1.0f / (w[0] + w[1] + w[2] + w[3]);
    float4 o0, o1;
    o0.x = v[0] * inv; o0.y = v[1] * inv; o0.z = v[2] * inv; o0.w = v[3] * inv;
    o1.x = v[4] * inv; o1.y = v[5] * inv; o1.z = v[6] * inv; o1.w = v[7] * inv;
    *reinterpret_cast<float4*>(&p[tid * 8])     = o0;
    *reinterpret_cast<float4*>(&p[tid * 8 + 4]) = o1;
    union { unsigned short u[8]; uint4 v4; } pk;
    pk.u[0] = f2bf(o0.x); pk.u[1] = f2bf(o0.y); pk.u[2] = f2bf(o0.z); pk.u[3] = f2bf(o0.w);
    pk.u[4] = f2bf(o1.x); pk.u[5] = f2bf(o1.y); pk.u[6] = f2bf(o1.z); pk.u[7] = f2bf(o1.w);
    *reinterpret_cast<uint4*>(&pb[tid * 8]) = pk.v4;
}

// Partial t-sums of attn: part[b][c][s] = sum_{t in chunk c} attnb[b][t][s].
// grid (XCH, B), 256 thr; fully-coalesced uint4 row reads.
__global__ __launch_bounds__(256) void k_xmean_part(const unsigned short* __restrict__ attnb,
                                                    float* __restrict__ part)
{
    const int c = blockIdx.x, b = blockIdx.y;
    const unsigned short* p = attnb + ((size_t)b * TT + (size_t)c * (TT / XCH)) * SS
                              + threadIdx.x * 8;
    float acc[8] = {0.f, 0.f, 0.f, 0.f, 0.f, 0.f, 0.f, 0.f};
    #pragma unroll 8
    for (int t = 0; t < TT / XCH; ++t) {
        union { unsigned short u[8]; uint4 v4; } ld;
        ld.v4 = *reinterpret_cast<const uint4*>(p + (size_t)t * SS);
        #pragma unroll
        for (int i = 0; i < 8; ++i) acc[i] += bf2f(ld.u[i]);
    }
    float* o = part + ((size_t)b * XCH + c) * SS + threadIdx.x * 8;
    #pragma unroll
    for (int i = 0; i < 8; ++i) o[i] = acc[i];
}

// ns[b,n,:] = enc_values[b, n*STRIDE, :]/||.||;  aa[b,n] = xmean[b, n*STRIDE]
// (aa summed inline from the XCH partials). Also zeroes klp.
__global__ __launch_bounds__(256) void k_ns(const float* __restrict__ ev,
                                            const float* __restrict__ part,
                                            float* __restrict__ ns, float* __restrict__ aa,
                                            float* __restrict__ klp)
{
    const int n = blockIdx.x, b = blockIdx.y;
    const int tid = threadIdx.x;
    if (n == 0 && b == 0 && tid == 0) klp[0] = 0.0f;
    const float* rowp = ev + ((size_t)b * SS + (size_t)n * STRIDE_) * EE;
    const float v = rowp[tid];
    __shared__ float w[4];
    float r = wave_sum(v * v);
    if ((tid & 63) == 0) w[tid >> 6] = r;
    float pv = (tid < XCH) ? part[((size_t)b * XCH + tid) * SS + n * STRIDE_] : 0.f;
    float psum = wave_sum(pv);          // valid in lane 0 of wave 0
    __syncthreads();
    const float nrm = sqrtf(w[0] + w[1] + w[2] + w[3]);
    ns[((size_t)b * NSUB + n) * EE + tid] = v / nrm;
    if (tid == 0) aa[b * NSUB + n] = psum * (1.0f / TT);
}

// L[b,i,j] = (aa_i*aa_j) * dot(ns_i, ns_j).  grid (N, B), 128 thr
__global__ __launch_bounds__(128) void k_L(const float* __restrict__ ns,
                                           const float* __restrict__ aa,
                                           float* __restrict__ Lm)
{
    const int i = blockIdx.x, b = blockIdx.y;
    const int tid = threadIdx.x;
    __shared__ float nsi[EE];
    nsi[tid]       = ns[((size_t)b * NSUB + i) * EE + tid];
    nsi[tid + 128] = ns[((size_t)b * NSUB + i) * EE + tid + 128];
    __syncthreads();
    const float ai = aa[b * NSUB + i];
    for (int j = tid; j < NSUB; j += 128) {
        const float* rj = ns + ((size_t)b * NSUB + j) * EE;
        float d = 0.f;
        #pragma unroll 4
        for (int e = 0; e < EE; ++e) d += nsi[e] * rj[e];
        Lm[((size_t)b * NSUB + i) * NSUB + j] = d * ai * aa[b * NSUB + j];
    }
}

// Greedy MAP DPP (Cholesky) + Gaussian-mixture dist + KL — one block per
// batch, 256 thr (bfgm phase uses the first 128, dist/KL phase uses all).
// mu never leaves LDS. klp pre-zeroed by k_ns (earlier on the stream).
__global__ __launch_bounds__(256) void k_bfgm_kl(const float* __restrict__ Lm,
                                                 const float* __restrict__ part,
                                                 float* __restrict__ outkl)
{
    const int b = blockIdx.x;
    const int tid = threadIdx.x;
    const float* L = Lm + (size_t)b * NSUB * NSUB;
    __shared__ float D[128], mask[128], Cm[128 * MAXS], cj[MAXS], musS[MAXS];
    __shared__ float rv[4];
    __shared__ int   ri[4];
    __shared__ int   Jsh;
    __shared__ float w[4];
    const bool half = tid < 128;
    const bool act  = tid < NSUB;
    if (half) {
        D[tid]    = act ? L[(size_t)tid * NSUB + tid] : 0.0f;
        mask[tid] = act ? 1.0f : 0.0f;
        #pragma unroll
        for (int k = 0; k < MAXS; ++k) Cm[tid * MAXS + k] = 0.0f;
    }
    __syncthreads();

    auto argmax_step = [&](int t) {
        float key = act ? logf(D[tid] * mask[tid]) : -INFINITY;
        if (isnan(key)) key = INFINITY;   // numpy argmax: NaN wins
        float v = key; int idx = tid;
        #pragma unroll
        for (int o = 32; o; o >>= 1) {
            float ov = __shfl_down(v, o); int oi = __shfl_down(idx, o);
            if (ov > v || (ov == v && oi < idx)) { v = ov; idx = oi; }
        }
        if ((tid & 63) == 0) { rv[tid >> 6] = v; ri[tid >> 6] = idx; }
        __syncthreads();
        if (tid == 0) {
            float bv = rv[0]; int bi = ri[0];
            #pragma unroll
            for (int q2 = 1; q2 < 4; ++q2)
                if (rv[q2] > bv || (rv[q2] == bv && ri[q2] < bi)) { bv = rv[q2]; bi = ri[q2]; }
            Jsh = bi; mask[bi] = 0.0f; musS[t] = (float)bi;
        }
        __syncthreads();
    };

    argmax_step(0);
    for (int t = 1; t < MAXS; ++t) {
        if (tid < MAXS) cj[tid] = Cm[Jsh * MAXS + tid];
        __syncthreads();
        const int J = Jsh;
        const float dj = D[J];
        float e = 0.0f;
        if (act) {
            const float Ljn = L[(size_t)J * NSUB + tid];
            float cd = 0.f;
            #pragma unroll
            for (int k = 0; k < MAXS; ++k) cd += Cm[tid * MAXS + k] * cj[k];
            e = (Ljn - cd) / dj * mask[tid];
        }
        if (half) { Cm[tid * MAXS + t] = e; D[tid] -= e * e; }
        __syncthreads();
        argmax_step(t);
    }

    // ---- dist softmax + KL (all 256 threads) ----
    float xm[8];
    #pragma unroll
    for (int i = 0; i < 8; ++i) {
        float s = 0.f;
        #pragma unroll 8
        for (int c2 = 0; c2 < XCH; ++c2)
            s += part[((size_t)b * XCH + c2) * SS + tid + (i << 8)];
        xm[i] = s * (1.0f / TT);
    }
    float g[8];
    float mx = -INFINITY;
    #pragma unroll
    for (int i = 0; i < 8; ++i) {
        const float s = (float)(tid + (i << 8));
        float acc = 0.f;
        #pragma unroll
        for (int m = 0; m < MAXS; ++m) { const float z = s - musS[m]; acc += expf(-(z * z) * INV2S2); }
        g[i] = acc * GNORM;
        mx = fmaxf(mx, g[i]);
    }
    float wm = wave_max(mx);
    if ((tid & 63) == 0) w[tid >> 6] = wm;
    __syncthreads();
    const float m = fmaxf(fmaxf(w[0], w[1]), fmaxf(w[2], w[3]));
    float sum = 0.f;
    #pragma unroll
    for (int i = 0; i < 8; ++i) { g[i] = expf(g[i] - m); sum += g[i]; }
    __syncthreads();
    float wsv = wave_sum(sum);
    if ((tid & 63) == 0) w[tid >> 6] = wsv;
    __syncthreads();
    const float inv = 1.0f / (w[0] + w[1] + w[2] + w[3]);
    float acc2 = 0.f;
    #pragma unroll
    for (int i = 0; i < 8; ++i)
        acc2 += xm[i] * (logf(xm[i]) - g[i] * inv);
    __syncthreads();
    float wp = wave_sum(acc2);
    if ((tid & 63) == 0) w[tid >> 6] = wp;
    __syncthreads();
    if (tid == 0) atomicAdd(outkl, -(w[0] + w[1] + w[2] + w[3]));
}

extern "C" void kernel_launch(void* const* d_in, const int* in_sizes, int n_in,
                              void* d_out, int out_size, void* d_ws, size_t ws_size,
                              hipStream_t stream)
{
    const float* x     = (const float*)d_in[0];   // (B,T,C)
    const float* te    = (const float*)d_in[1];   // (B,T,E)
    const float* keys  = (const float*)d_in[2];   // (B,E,S)
    const float* vals  = (const float*)d_in[3];   // (B,S,E)
    const float* W_in  = (const float*)d_in[4];   // (E,C)
    const float* b_in  = (const float*)d_in[5];   // (E)
    const float* W_out = (const float*)d_in[6];   // (C,E)
    const float* b_out = (const float*)d_in[7];   // (C)

    float* outp = (float*)d_out;                       // (B,T,C)
    float* attn = outp + (size_t)BB * TT * CC;         // (B,T,S) fp32
    float* klp  = attn + (size_t)BB * TT * SS;         // scalar

    // workspace
    unsigned short* X       = (unsigned short*)d_ws;
    unsigned short* x_bf    = X;                                       // B*T*C
    unsigned short* Win_bf  = x_bf   + (size_t)BB * TT * CC;           // E*C
    unsigned short* Wout_bf = Win_bf + (size_t)EE * CC;                // C*E
    unsigned short* h_bf    = Wout_bf+ (size_t)CC * EE;                // B*T*E
    unsigned short* keysT   = h_bf   + (size_t)BB * TT * EE;           // B*S*E
    unsigned short* valsT   = keysT  + (size_t)BB * SS * EE;           // B*E*S
    unsigned short* attnb   = valsT  + (size_t)BB * EE * SS;           // B*T*S (scores, then attn)
    unsigned short* mid_bf  = attnb  + (size_t)BB * TT * SS;           // B*T*E
    float* fws   = (float*)(mid_bf + (size_t)BB * TT * EE + 8);
    float* part  = fws;                                  // (B,XCH,S)
    float* ns    = part  + (size_t)BB * XCH * SS;        // (B,N,E)
    float* aa    = ns    + (size_t)BB * NSUB * EE;       // (B,N)
    float* Lm    = aa    + (size_t)BB * NSUB;            // (B,N,N)

    // casts (x, W_in, W_out in one launch)
    {
        const int na = BB * TT * CC / 4, nb = EE * CC / 4, nc = CC * EE / 4;
        const int blocks = (na + nb + nc + 255) / 256;
        k_cast3<<<blocks, 256, 0, stream>>>(x, x_bf, na, W_in, Win_bf, nb, W_out, Wout_bf, nc);
    }
    // 1) h_bf = bf16((x @ W_in^T + b_in + te) * sqrt(.5))   [64x64, 1024 blocks]
    k_gemm<64, 64, 2><<<dim3(256, 4, 1), 256, 0, stream>>>(
        x_bf, Win_bf, b_in, te, nullptr, h_bf, BB * TT, CC, CC, 1.0f);
    // 2) keysT[b,s,e] = keys[b,e,s] (bf16)
    k_transpose_bf16<<<dim3(4, 32, BB), 256, 0, stream>>>(keys, keysT, EE, SS);
    // 3) scores (bf16) -> attnb   [128x128, 2048 blocks]
    k_gemm<128, 128, 3><<<dim3(8, 16, BB), 256, 0, stream>>>(
        h_bf, keysT, nullptr, nullptr, nullptr, attnb, TT, SS, EE, 1.0f);
    // 4) valsT[b,e,s] = vals[b,s,e] (bf16)
    k_transpose_bf16<<<dim3(32, 4, BB), 256, 0, stream>>>(vals, valsT, SS, EE);
    // 5) softmax: attnb(scores bf16) -> attn fp32 (output) + attnb bf16 in place
    k_softmax<<<BB * TT, 256, 0, stream>>>(attn, attnb);
    // 6) x_mean partials from bf16 attn   [512 blocks]
    k_xmean_part<<<dim3(XCH, BB), 256, 0, stream>>>(attnb, part);
    // 7) DPP chain (k_ns zeroes klp for the k_bfgm_kl atomics)
    k_ns<<<dim3(NSUB, BB), 256, 0, stream>>>(vals, part, ns, aa, klp);
    k_L<<<dim3(NSUB, BB), 128, 0, stream>>>(ns, aa, Lm);
    k_bfgm_kl<<<BB, 256, 0, stream>>>(Lm, part, klp);
    // 8) mid_bf = bf16((attn @ enc_values) * sqrt(S))   [64x128, 512 blocks]
    k_gemm<64, 128, 3><<<dim3(16, 2, BB), 256, 0, stream>>>(
        attnb, valsT, nullptr, nullptr, nullptr, mid_bf, TT, EE, SS, SQRT_S);
    // 9) out = (mid @ W_out^T + b_out + x) * sqrt(.5)   [64x64, 1024 blocks]
    k_gemm<64, 64, 1><<<dim3(256, 4, 1), 256, 0, stream>>>(
        mid_bf, Wout_bf, b_out, x, outp, nullptr, BB * TT, CC, CC, 1.0f);
}